// Round 13
// baseline (630.233 us; speedup 1.0000x reference)
//
#include <hip/hip_runtime.h>

// ---------------------------------------------------------------------------
// NaryCompUSchema: embed -> 3x masked LSTM (last hidden) -> segment_sum -> BPR
//   P[v, 0:1024]   = embed[v] @ col_W_ih^T + (col_b_ih + col_b_hh)   (bf16)
//   P[v,1024:2048] = embed[v] @ row_W_ih^T + (row_b_ih + row_b_hh)
//   Recurrence: gates^T = W_hh * h^T via mfma_f32_16x16x32_bf16.
// R13: lstm FROZEN at R12 (365us, verified). gemm_p v4 attacks the P-store
// pattern (was 64 scalar ushort stores/thread/nc, 4-row scatter = 4x write
// transactions on a write-bound kernel):
//   - M-tile 64 (grid 782), At 40KB
//   - epilogue stages 64x128 tile in LDS (64x132 ushort, ~2-way banks),
//     then fully-coalesced dwordx2 global stores (512B/wave-instr)
//   - LDS 57KB -> 2 blocks/CU; Bpk repacked for 4 column-waves (same bytes)
// ---------------------------------------------------------------------------

typedef __bf16 bf16x8 __attribute__((ext_vector_type(8)));
typedef float  fvec4  __attribute__((ext_vector_type(4)));

#define NSEN 4096
#define HIDN 256
#define EMBD 300
#define VOC  50000

// workspace layout (bytes)
#define OFF_P     0ULL            // ushort [50000][2048]
#define OFF_BPK   204800000ULL    // ushort [1280][512]   (packed W_ih frags)
#define OFF_WHHC  206110720ULL    // ushort [262144]      (packed frag order)
#define OFF_WHHR  206635008ULL    // ushort [262144]      (packed frag order)
#define OFF_BIAS  207159296ULL    // float  [2048]
#define OFF_SEG   219750400ULL    // float  [3][4096][256]
#define OFF_LOSS  232333312ULL    // float  [4096]

static __device__ __forceinline__ unsigned short f2bf(float x) {
    unsigned int u = __float_as_uint(x);
    unsigned int r = (u + 0x7fffu + ((u >> 16) & 1u)) >> 16;  // RNE
    return (unsigned short)r;
}
static __device__ __forceinline__ float bf2f(unsigned short b) {
    return __uint_as_float(((unsigned int)b) << 16);
}
static __device__ __forceinline__ float sigm(float x) { return 1.f / (1.f + __expf(-x)); }
static __device__ __forceinline__ float tanh_(float x) {
    float e = __expf(2.f * x);
    return 1.f - 2.f / (e + 1.f);   // stable at +-inf
}
static __device__ __forceinline__ fvec4 unpk(uint2 v) {
    fvec4 o;
    o[0] = __uint_as_float((v.x & 0xffffu) << 16);
    o[1] = __uint_as_float(v.x & 0xffff0000u);
    o[2] = __uint_as_float((v.y & 0xffffu) << 16);
    o[3] = __uint_as_float(v.y & 0xffff0000u);
    return o;
}

// async 16B/lane gather into wave-private LDS (lane-ordered linear dest)
static __device__ __forceinline__ void gld_lds16(const unsigned short* g,
                                                 unsigned short* l)
{
    __builtin_amdgcn_global_load_lds(
        (const __attribute__((address_space(1))) unsigned int*)g,
        (__attribute__((address_space(3))) unsigned int*)l, 16, 0, 0);
}

// Whh packed layout (16-wave): frag L = (wv<<5)|(kt<<2)|g, elem = L*512+ln*8+j
// lane ln holds Whh[row][col], row = g*256 + wv*16 + (ln&15),
//                              col = kt*32 + (ln>>4)*8 + j
static __device__ __forceinline__ int whh_src(int o) {
    int L  = o >> 9;
    int r9 = o & 511;
    int ln = r9 >> 3, j = r9 & 7;
    int g  = L & 3, kt = (L >> 2) & 7, wv = (L >> 5) & 15;
    int row = g * 256 + wv * 16 + (ln & 15);
    int col = kt * 32 + (ln >> 4) * 8 + j;
    return row * 256 + col;
}

// ---------------------------------------------------------------- prep: pack
__global__ void prep_kernel(
    const float* __restrict__ cWih, const float* __restrict__ rWih,
    const float* __restrict__ cWhh, const float* __restrict__ rWhh,
    const float* __restrict__ cbih, const float* __restrict__ cbhh,
    const float* __restrict__ rbih, const float* __restrict__ rbhh,
    unsigned short* __restrict__ Bpk, unsigned short* __restrict__ WhhC,
    unsigned short* __restrict__ WhhR, float* __restrict__ biascat)
{
    int idx = blockIdx.x * 256 + threadIdx.x;
    if (idx < 655360) {
        // Bpk: frag f = ((s)*10 + kt)*2 + ntt, s = nc*4+wn ; elem e = ln*8+j
        // lane ln holds Wih_cat[n][k], n = s*32 + ntt*16 + (ln&15),
        //                              k = kt*32 + (ln>>4)*8 + j
        int e = idx & 511, lnn = e >> 3, j = e & 7;
        int f = idx >> 9;
        int ntt = f & 1;
        int kc = f >> 1;            // s*10 + kt
        int kt = kc % 10;
        int s  = kc / 10;           // 0..63
        int n = s * 32 + ntt * 16 + (lnn & 15);
        int k = kt * 32 + (lnn >> 4) * 8 + j;
        float v = 0.f;
        if (k < EMBD) v = (n < 1024) ? cWih[n * EMBD + k] : rWih[(n - 1024) * EMBD + k];
        Bpk[idx] = f2bf(v);
        return;
    }
    idx -= 655360;
    if (idx < 262144) { WhhC[idx] = f2bf(cWhh[whh_src(idx)]); return; }
    idx -= 262144;
    if (idx < 262144) { WhhR[idx] = f2bf(rWhh[whh_src(idx)]); return; }
    idx -= 262144;
    if (idx < 2048)
        biascat[idx] = (idx < 1024) ? (cbih[idx] + cbhh[idx])
                                    : (rbih[idx - 1024] + rbhh[idx - 1024]);
}

// ------------------------------------------------------- P = embed @ Wcat^T
// v4: grid 782; block owns 64 M-rows x full N=2048. A staged once in 40KB
// LDS; per-nc output staged in padded LDS tile -> coalesced dwordx2 stores.
__global__ __launch_bounds__(256) void gemm_p_kernel(
    const float* __restrict__ A,          // embed [50000][300] fp32
    const unsigned short* __restrict__ Bpk,
    const float* __restrict__ bias,       // [2048]
    unsigned short* __restrict__ Pout)    // [50000][2048] bf16
{
    const int mb = blockIdx.x * 64;
    const int tid = threadIdx.x;
    const int wv = tid >> 6, ln = tid & 63, l15 = ln & 15, q = ln >> 4;
    // wave wv owns output cols [wv*32, wv*32+32) of each 128-col nc chunk

    // A frags: At[mt][kt][512]; lane lnn holds A[row][k],
    // row = mt*16+(lnn&15), k = kt*32+(lnn>>4)*8+j      (40 KB)
    __shared__ __align__(16) unsigned short At[4][10][512];
    __shared__ __align__(16) unsigned short tile[64 * 132];   // 16.9 KB, pad 132
    char* tileB = (char*)&tile[0];

    {   // stage A: thread t covers row = t>>2, k in [ (t&3)*80, +80 )
        int row = tid >> 2, kh = tid & 3;
        int gr = mb + row;
        const int fl = row & 15;
        unsigned short* dst = &At[row >> 4][0][0];
        #pragma unroll
        for (int i = 0; i < 20; ++i) {
            int k = kh * 80 + i * 4;
            float4 v = make_float4(0.f, 0.f, 0.f, 0.f);
            if (gr < VOC && k < EMBD)
                v = *(const float4*)(A + (size_t)gr * EMBD + k);
            ushort4 b;
            b.x = f2bf(v.x); b.y = f2bf(v.y); b.z = f2bf(v.z); b.w = f2bf(v.w);
            int di = (k >> 5) * 512 + ((k >> 3) & 3) * 128 + fl * 8 + (k & 7);
            *(ushort4*)(dst + di) = b;
        }
    }
    __syncthreads();

    for (int nc = 0; nc < 16; ++nc) {
        fvec4 acc[4][2];   // [mt][ntt]
        #pragma unroll
        for (int a = 0; a < 4; ++a)
            #pragma unroll
            for (int b = 0; b < 2; ++b) acc[a][b] = (fvec4)0.f;

        #pragma unroll 2
        for (int kt = 0; kt < 10; ++kt) {
            const unsigned short* bp =
                Bpk + (size_t)((((nc * 4 + wv) * 10 + kt) * 2)) * 512 + ln * 8;
            bf16x8 bfr[2];
            bfr[0] = *(const bf16x8*)(bp);
            bfr[1] = *(const bf16x8*)(bp + 512);
            #pragma unroll
            for (int mt = 0; mt < 4; ++mt) {
                bf16x8 af = *(const bf16x8*)&At[mt][kt][ln * 8];
                acc[mt][0] = __builtin_amdgcn_mfma_f32_16x16x32_bf16(af, bfr[0], acc[mt][0], 0, 0, 0);
                acc[mt][1] = __builtin_amdgcn_mfma_f32_16x16x32_bf16(af, bfr[1], acc[mt][1], 0, 0, 0);
            }
        }

        __syncthreads();   // previous nc's tile reads complete
        #pragma unroll
        for (int mt = 0; mt < 4; ++mt)
            #pragma unroll
            for (int ntt = 0; ntt < 2; ++ntt) {
                float bv = bias[nc * 128 + wv * 32 + ntt * 16 + l15];
                #pragma unroll
                for (int r = 0; r < 4; ++r)
                    *(unsigned short*)(tileB + (mt * 16 + q * 4 + r) * 264 +
                                       (wv * 32 + ntt * 16 + l15) * 2)
                        = f2bf(acc[mt][ntt][r] + bv);
            }
        __syncthreads();   // tile writes visible

        // coalesced store: 64 rows x 128 cols; 8B chunks, 512B/wave-instr
        #pragma unroll
        for (int it = 0; it < 8; ++it) {
            int i = tid + it * 256;        // 0..2047
            int row = i >> 5, ch = i & 31;
            uint2 v = *(const uint2*)(tileB + row * 264 + ch * 8);
            int m = mb + row;
            if (m < VOC)
                *(uint2*)(Pout + (size_t)m * 2048 + nc * 128 + ch * 4) = v;
        }
    }
}

// ----------------------------------------------------------------- LSTMs
// grid 768 x 1024: blocks [0,256) col, [256,512) row, [512,768) row_neg.
// Block: 16 seqs, 16 waves; wave wv owns hidden units [16wv, 16wv+16).
// kt0-3 W frags register-resident (loaded once); kt4-7 streamed from L2.
// acc 0-init; P added post-kt-loop (gather latency hidden under MFMAs).
// FROZEN from R12 (verified 365us).
__global__ __launch_bounds__(1024, 2) void lstm_kernel(
    const int* __restrict__ colTok, const int* __restrict__ rowTok, const int* __restrict__ negTok,
    const int* __restrict__ colLen, const int* __restrict__ rowLen, const int* __restrict__ negLen,
    const int* __restrict__ crefs, const int* __restrict__ rrefs, const int* __restrict__ nrefs,
    const unsigned short* __restrict__ P,
    const unsigned short* __restrict__ WhhC, const unsigned short* __restrict__ WhhR,
    float* __restrict__ seg)
{
    const int part = blockIdx.x >> 8;
    const int sb = blockIdx.x & 255;
    const int s0 = sb * 16;
    const int* tok = part == 0 ? colTok : (part == 1 ? rowTok : negTok);
    const int* len = part == 0 ? colLen : (part == 1 ? rowLen : negLen);
    const int* refs = part == 0 ? crefs : (part == 1 ? rrefs : nrefs);
    const unsigned short* Whh = part == 0 ? WhhC : WhhR;
    const int T = part == 0 ? 64 : 16;
    const int pco = part == 0 ? 0 : 1024;
    float* segp = seg + (size_t)part * 1048576;

    const int tid = threadIdx.x;
    const int wv = tid >> 6;            // 0..15
    const int ln = tid & 63, l15 = ln & 15, q = ln >> 4;

    __shared__ __align__(16) unsigned short hx[2][8][4][16][8];       // 16 KB
    __shared__ __align__(16) unsigned short pstage[16][4][2][16][8];  // 32 KB
    char* hB0 = (char*)&hx[0][0][0][0][0];
    char* hB1 = (char*)&hx[1][0][0][0][0];

    for (int i = tid; i < 8192; i += 1024) (&hx[0][0][0][0][0])[i] = 0;

    // lens in regs: per-lane load + shfl-xor max over the 16 seqs
    const int len0 = len[s0 + l15];
    int ml = len0;
    #pragma unroll
    for (int off = 1; off < 16; off <<= 1) ml = max(ml, __shfl_xor(ml, off));
    const int maxlen = ml;

    // per-wave contiguous packed-Whh stream base (32 KB per wave per step)
    const unsigned short* wbase = Whh + (size_t)wv * 16384 + (size_t)ln * 8;

    // h write byte: unit u = wv*16 + q*4 + r -> kt = wv>>1,
    // qc = (wv&1)*2 + (q>>1), j = (q&1)*4 + r ; seq = l15
    const int wrByte = (wv >> 1) * 1024 + ((wv & 1) * 2 + (q >> 1)) * 256 +
                       l15 * 16 + (q & 1) * 8;

    // DMA lane mapping: instr d stages gates 2d,2d+1 (1KB, dest lane-linear):
    // lane ln -> gate = 2d + (ln>>5), half = (ln>>4)&1, seq = ln&15
    const int dg = ln >> 5, dh = (ln >> 4) & 1;

    float c[4];
    #pragma unroll
    for (int r = 0; r < 4; ++r) c[r] = 0.f;
    ushort4 hpk = make_ushort4(0, 0, 0, 0);

    // ---- resident W half: kt 0..3, loaded ONCE (16 frags = 64 VGPR)
    bf16x8 wres[4][4];
    #pragma unroll
    for (int kt = 0; kt < 4; ++kt)
        #pragma unroll
        for (int g = 0; g < 4; ++g)
            wres[kt][g] = *(const bf16x8*)(wbase + (size_t)(kt * 4 + g) * 512);

    __syncthreads();   // hx zero-init visible

    // ---- prologue: DMA-stage P rows for t=0
    {
        int tk = tok[(s0 + l15) * T];
        #pragma unroll
        for (int d = 0; d < 2; ++d) {
            const unsigned short* src = P + (size_t)tk * 2048 + pco +
                (2 * d + dg) * 256 + wv * 16 + dh * 8;
            gld_lds16(src, &pstage[wv][2 * d][0][0][0]);
        }
    }
    int tknext = tok[(s0 + l15) * T + 1];   // T >= 16

    for (int t = 0; t < maxlen; ++t) {
        const char* hRd = (t & 1) ? hB1 : hB0;
        char* hWr = (t & 1) ? hB0 : hB1;

        // acc 0-init: MFMAs start immediately, no VMEM dependency
        fvec4 acc[4];
        #pragma unroll
        for (int g = 0; g < 4; ++g) acc[g] = (fvec4)0.f;

        // resident half (register-fed; covers streamed-half load latency)
        #pragma unroll
        for (int kt = 0; kt < 4; ++kt) {
            bf16x8 b0 = *(const bf16x8*)(hRd + kt * 1024 + ln * 16);
            #pragma unroll
            for (int g = 0; g < 4; ++g)
                acc[g] = __builtin_amdgcn_mfma_f32_16x16x32_bf16(
                    wres[kt][g], b0, acc[g], 0, 0, 0);
        }
        // streamed half (16 L2 loads, compiler-scheduled)
        #pragma unroll 2
        for (int kt = 4; kt < 8; ++kt) {
            bf16x8 b0 = *(const bf16x8*)(hRd + kt * 1024 + ln * 16);
            #pragma unroll
            for (int g = 0; g < 4; ++g) {
                bf16x8 a = *(const bf16x8*)(wbase + (size_t)(kt * 4 + g) * 512);
                acc[g] = __builtin_amdgcn_mfma_f32_16x16x32_bf16(a, b0, acc[g], 0, 0, 0);
            }
        }

        // P contribution: the t-gather had the whole kt loop to land
        asm volatile("s_waitcnt vmcnt(0)" ::: "memory");
        #pragma unroll
        for (int g = 0; g < 4; ++g) {
            fvec4 pv = unpk(*(const uint2*)
                &pstage[wv][g][q >> 1][l15][(q & 1) * 4]);
            acc[g] += pv;
        }

        // issue next step's DMAs (single pstage buffer; reads just drained)
        if (t + 1 < maxlen) {
            asm volatile("s_waitcnt lgkmcnt(0)" ::: "memory");
            __builtin_amdgcn_sched_barrier(0);
            #pragma unroll
            for (int d = 0; d < 2; ++d) {
                const unsigned short* src = P + (size_t)tknext * 2048 + pco +
                    (2 * d + dg) * 256 + wv * 16 + dh * 8;
                gld_lds16(src, &pstage[wv][2 * d][0][0][0]);
            }
            int t2 = (t + 2 < T) ? (t + 2) : (T - 1);
            tknext = tok[(s0 + l15) * T + t2];
        }

        // activation + h write to the other buffer (frozen lanes rewrite hpk)
        {
            bool act = t < len0;
            if (act) {
                float hr[4];
                #pragma unroll
                for (int r = 0; r < 4; ++r) {
                    float iv = acc[0][r];
                    float fv = acc[1][r];
                    float gv = acc[2][r];
                    float ov = acc[3][r];
                    float cn = sigm(fv) * c[r] + sigm(iv) * tanh_(gv);
                    c[r] = cn;
                    hr[r] = sigm(ov) * tanh_(cn);
                }
                hpk = make_ushort4(f2bf(hr[0]), f2bf(hr[1]),
                                   f2bf(hr[2]), f2bf(hr[3]));
            }
            *(ushort4*)(hWr + wrByte) = hpk;
        }
        // ONE barrier per step: h writes visible before next step's reads
        asm volatile("s_waitcnt lgkmcnt(0)\n\ts_barrier" ::: "memory");
    }

    // fused segment-sum epilogue: h -> atomicAdd into seg[part]
    const char* hF = (maxlen & 1) ? hB1 : hB0;
    for (int i = tid; i < 16 * HIDN; i += 1024) {
        int sq = i >> 8, hd = i & 255;
        unsigned short hv = *(const unsigned short*)
            (hF + (hd >> 5) * 1024 + ((hd >> 3) & 3) * 256 +
             sq * 16 + (hd & 7) * 2);
        int rf = refs[s0 + sq];
        atomicAdd(segp + (size_t)rf * 256 + hd, bf2f(hv));
    }
}

// ------------------------------------------------------------------ loss
__global__ void loss_kernel(const float* __restrict__ seg, float* __restrict__ part)
{
    int d = blockIdx.x, tid = threadIdx.x;
    const float* sc = seg + (size_t)d * 256;
    const float* sr = seg + 1048576 + (size_t)d * 256;
    const float* sn = seg + 2097152 + (size_t)d * 256;
    float a = sc[tid];
    float p = a * sr[tid];
    float n = a * sn[tid];
    for (int off = 32; off; off >>= 1) { p += __shfl_down(p, off); n += __shfl_down(n, off); }
    __shared__ float rp[4], rn[4];
    if ((tid & 63) == 0) { rp[tid >> 6] = p; rn[tid >> 6] = n; }
    __syncthreads();
    if (tid == 0) {
        float Ps = rp[0] + rp[1] + rp[2] + rp[3];
        float Ns = rn[0] + rn[1] + rn[2] + rn[3];
        float x = Ps - Ns;
        part[d] = fmaxf(-x, 0.f) + log1pf(expf(-fabsf(x)));  // softplus(-x)
    }
}

__global__ void reduce_kernel(const float* __restrict__ part, float* __restrict__ out)
{
    int tid = threadIdx.x;
    float s = 0.f;
    for (int i = tid; i < 4096; i += 256) s += part[i];
    for (int off = 32; off; off >>= 1) s += __shfl_down(s, off);
    __shared__ float r[4];
    if ((tid & 63) == 0) r[tid >> 6] = s;
    __syncthreads();
    if (tid == 0) out[0] = r[0] + r[1] + r[2] + r[3];
}

// ---------------------------------------------------------------------------
extern "C" void kernel_launch(void* const* d_in, const int* in_sizes, int n_in,
                              void* d_out, int out_size, void* d_ws, size_t ws_size,
                              hipStream_t stream)
{
    const int*   col      = (const int*)d_in[0];
    const int*   row      = (const int*)d_in[1];
    const int*   rneg     = (const int*)d_in[2];
    const int*   col_lens = (const int*)d_in[3];
    const int*   row_lens = (const int*)d_in[4];
    const int*   rng_lens = (const int*)d_in[5];
    const int*   col_refs = (const int*)d_in[6];
    const int*   row_refs = (const int*)d_in[7];
    const int*   rng_refs = (const int*)d_in[8];
    const float* embed    = (const float*)d_in[9];
    const float* cWih     = (const float*)d_in[10];
    const float* cWhh     = (const float*)d_in[11];
    const float* cbih     = (const float*)d_in[12];
    const float* cbhh     = (const float*)d_in[13];
    const float* rWih     = (const float*)d_in[14];
    const float* rWhh     = (const float*)d_in[15];
    const float* rbih     = (const float*)d_in[16];
    const float* rbhh     = (const float*)d_in[17];

    char* ws = (char*)d_ws;
    unsigned short* P    = (unsigned short*)(ws + OFF_P);
    unsigned short* Bpk  = (unsigned short*)(ws + OFF_BPK);
    unsigned short* WhhC = (unsigned short*)(ws + OFF_WHHC);
    unsigned short* WhhR = (unsigned short*)(ws + OFF_WHHR);
    float* biascat = (float*)(ws + OFF_BIAS);
    float* seg     = (float*)(ws + OFF_SEG);
    float* lpart   = (float*)(ws + OFF_LOSS);

    hipMemsetAsync(seg, 0, 3 * 4096 * 256 * sizeof(float), stream);

    prep_kernel<<<4616, 256, 0, stream>>>(cWih, rWih, cWhh, rWhh,
                                          cbih, cbhh, rbih, rbhh,
                                          Bpk, WhhC, WhhR, biascat);
    gemm_p_kernel<<<782, 256, 0, stream>>>(embed, Bpk, biascat, P);
    lstm_kernel<<<768, 1024, 0, stream>>>(col, row, rneg,
                                          col_lens, row_lens, rng_lens,
                                          col_refs, row_refs, rng_refs,
                                          P, WhhC, WhhR, seg);
    loss_kernel<<<4096, 256, 0, stream>>>(seg, lpart);
    reduce_kernel<<<1, 256, 0, stream>>>(lpart, (float*)d_out);
}